// Round 16
// baseline (254.078 us; speedup 1.0000x reference)
//
#include <hip/hip_runtime.h>

typedef unsigned long long u64;
typedef unsigned int u32;

#define B_SZ   8
#define N_ANC  36864
#define N_PRE  12000
#define N_POST 2000
#define SEG    2048
#define NSEG   6
#define MAXC   (SEG * NSEG)   // 12288
#define NW     (SEG / 64)     // 32 u64 words per mask row
#define NDW    (MAXC / 64)    // 192 dead-mask words per batch
#define NBLK   144            // decode/scatter blocks per batch

__device__ __forceinline__ float area_of(float4 p) {
  return __fmul_rn(__fsub_rn(p.z, p.x), __fsub_rn(p.w, p.y));
}

// bit-exact replication: a0 = area(first reference arg), a1 = area(second)
__device__ __forceinline__ bool iou_gt_a(float4 p, float4 q, float a0, float a1) {
  float ix1 = fmaxf(p.x, q.x), iy1 = fmaxf(p.y, q.y);
  float ix2 = fminf(p.z, q.z), iy2 = fminf(p.w, q.w);
  float iw = fmaxf(__fsub_rn(ix2, ix1), 0.0f);
  float ih = fmaxf(__fsub_rn(iy2, iy1), 0.0f);
  float inter = __fmul_rn(iw, ih);
  float den = fmaxf(__fsub_rn(__fadd_rn(a0, a1), inter), 1e-9f);
  return (inter / den) > 0.7f;
}

// ---------------- decode + score + keys + fused level-1 histogram -------
__global__ __launch_bounds__(256) void k_decode(
    const int* __restrict__ imh_p, const int* __restrict__ imw_p,
    const float* __restrict__ anchors, const float* __restrict__ loc,
    const float* __restrict__ obj, float4* __restrict__ boxes,
    u64* __restrict__ keys, u32* __restrict__ hist)
{
  __shared__ u32 lh[2048];
  int t = threadIdx.x;
#pragma unroll
  for (int i = 0; i < 8; ++i) lh[t + i * 256] = 0;
  __syncthreads();

  int n = blockIdx.x * 256 + t;
  int b = blockIdx.y;
  float a0 = anchors[n * 4 + 0], a1 = anchors[n * 4 + 1];
  float a2 = anchors[n * 4 + 2], a3 = anchors[n * 4 + 3];
  size_t off = (size_t)b * N_ANC + n;
  float l0 = loc[off * 4 + 0], l1 = loc[off * 4 + 1];
  float l2 = loc[off * 4 + 2], l3 = loc[off * 4 + 3];

  float w  = __fsub_rn(a2, a0);
  float h  = __fsub_rn(a3, a1);
  float cx = __fadd_rn(a0, __fmul_rn(0.5f, w));
  float cy = __fadd_rn(a1, __fmul_rn(0.5f, h));
  float pcx = __fadd_rn(__fmul_rn(l0, w), cx);
  float pcy = __fadd_rn(__fmul_rn(l1, h), cy);
  float pw  = __fmul_rn(expf(l2), w);
  float ph  = __fmul_rn(expf(l3), h);
  float imw = (float)imw_p[0], imh = (float)imh_p[0];
  float hx = __fmul_rn(0.5f, pw), hy = __fmul_rn(0.5f, ph);
  float x1 = fminf(fmaxf(__fsub_rn(pcx, hx), 0.0f), imw);
  float y1 = fminf(fmaxf(__fsub_rn(pcy, hy), 0.0f), imh);
  float x2 = fminf(fmaxf(__fadd_rn(pcx, hx), 0.0f), imw);
  float y2 = fminf(fmaxf(__fadd_rn(pcy, hy), 0.0f), imh);
  boxes[off] = make_float4(x1, y1, x2, y2);

  bool valid = (__fsub_rn(x2, x1) >= 16.0f) && (__fsub_rn(y2, y1) >= 16.0f);

  float o0 = obj[off * 2 + 0], o1 = obj[off * 2 + 1];
  float m  = fmaxf(o0, o1);
  float e0 = expf(__fsub_rn(o0, m));
  float e1 = expf(__fsub_rn(o1, m));
  float s  = e1 / __fadd_rn(e0, e1);
  float sc = valid ? s : -1e9f;

  u32 u  = __float_as_uint(sc);
  u32 fk = (u & 0x80000000u) ? ~u : (u | 0x80000000u);
  u32 sk = ~fk;  // ascending u64 == descending score, stable by index
  u64 key = ((u64)sk << 32) | (u32)n;
  keys[off] = key;
  atomicAdd(&lh[(u32)(key >> 53)], 1u);
  __syncthreads();
#pragma unroll
  for (int i = 0; i < 8; ++i) {
    u32 v = lh[t + i * 256];
    if (v) atomicAdd(&hist[b * 2048 + t + i * 256], v);
  }
}

// -------- level-1 pick; emits T2 directly when bin fits (gate lvl-2) ----
__global__ __launch_bounds__(256) void k_pick1(
    const u32* __restrict__ hist, u32* __restrict__ T1, u32* __restrict__ Base1,
    u32* __restrict__ T2, u32* __restrict__ need2)
{
  int b = blockIdx.x, t = threadIdx.x;
  const u32* h = hist + b * 2048;
  __shared__ u32 part[256], pre[256];
  u32 loc[8], s = 0;
#pragma unroll
  for (int i = 0; i < 8; ++i) { loc[i] = h[t * 8 + i]; s += loc[i]; }
  part[t] = s;
  __syncthreads();
  if (t == 0) { u32 acc = 0; for (int i = 0; i < 256; ++i) { pre[i] = acc; acc += part[i]; } }
  __syncthreads();
  u32 acc = pre[t];
#pragma unroll
  for (int i = 0; i < 8; ++i) {
    u32 na = acc + loc[i];
    if (acc < N_PRE && na >= N_PRE) {
      u32 bin = (u32)(t * 8 + i);
      T1[b] = bin; Base1[b] = acc;
      if (na <= MAXC) T2[b] = (bin << 11) | 0x7FFu;  // whole bin fits
      else need2[b] = 1;                              // refine (rare)
    }
    acc = na;
  }
}

// ---------------- level-2 histogram (gated) -----------------------------
__global__ __launch_bounds__(256) void k_hist2(
    const u64* __restrict__ keys, const u32* __restrict__ T1,
    const u32* __restrict__ need2, u32* __restrict__ hist)
{
  int b = blockIdx.y;
  if (!need2[b]) return;
  u32 t1 = T1[b];
  __shared__ u32 lh[2048];
  int t = threadIdx.x;
#pragma unroll
  for (int i = 0; i < 8; ++i) lh[t + i * 256] = 0;
  __syncthreads();
#pragma unroll
  for (int k = 0; k < 4; ++k) {
    int i = blockIdx.x * 1024 + k * 256 + t;
    u64 key = keys[(size_t)b * N_ANC + i];
    if ((u32)(key >> 53) == t1) atomicAdd(&lh[(u32)(key >> 42) & 0x7FFu], 1u);
  }
  __syncthreads();
#pragma unroll
  for (int i = 0; i < 8; ++i) {
    u32 v = lh[t + i * 256];
    if (v) atomicAdd(&hist[b * 2048 + t + i * 256], v);
  }
}

__global__ __launch_bounds__(256) void k_pick2(
    const u32* __restrict__ hist, const u32* __restrict__ T1,
    const u32* __restrict__ Base1, const u32* __restrict__ need2,
    u32* __restrict__ T2)
{
  int b = blockIdx.x, t = threadIdx.x;
  if (!need2[b]) return;
  const u32* h = hist + b * 2048;
  __shared__ u32 part[256], pre[256];
  u32 loc[8], s = 0;
#pragma unroll
  for (int i = 0; i < 8; ++i) { loc[i] = h[t * 8 + i]; s += loc[i]; }
  part[t] = s;
  __syncthreads();
  if (t == 0) { u32 acc = Base1[b]; for (int i = 0; i < 256; ++i) { pre[i] = acc; acc += part[i]; } }
  __syncthreads();
  u32 acc = pre[t];
#pragma unroll
  for (int i = 0; i < 8; ++i) {
    u32 na = acc + loc[i];
    if (acc < N_PRE && na >= N_PRE) T2[b] = (T1[b] << 11) | (u32)(t * 8 + i);
    acc = na;
  }
}

// ---------------- compact: count -> scatter (scatter self-scans) --------
__global__ __launch_bounds__(256) void k_count(
    const u64* __restrict__ keys, const u32* __restrict__ T2,
    u32* __restrict__ bcnt)
{
  int b = blockIdx.y;
  int i = blockIdx.x * 256 + threadIdx.x;
  u64 key = keys[(size_t)b * N_ANC + i];
  bool pred = (u32)(key >> 42) <= T2[b];
  u64 bal = __ballot(pred);
  __shared__ u32 wc[4];
  int wv = threadIdx.x >> 6, lane = threadIdx.x & 63;
  if (lane == 0) wc[wv] = (u32)__popcll(bal);
  __syncthreads();
  if (threadIdx.x == 0)
    bcnt[b * NBLK + blockIdx.x] = wc[0] + wc[1] + wc[2] + wc[3];
}

__global__ __launch_bounds__(256) void k_scatter(
    const u64* __restrict__ keys, const u32* __restrict__ T2,
    const u32* __restrict__ bcnt, u64* __restrict__ cand)
{
  int b = blockIdx.y, bx = blockIdx.x;
  int t = threadIdx.x;
  __shared__ u32 cnts[NBLK];
  __shared__ u32 wc[4];
  __shared__ u32 sbase;
  if (t < NBLK) cnts[t] = bcnt[b * NBLK + t];
  u64 key = keys[(size_t)b * N_ANC + bx * 256 + t];
  bool pred = (u32)(key >> 42) <= T2[b];
  u64 bal = __ballot(pred);
  int wv = t >> 6, lane = t & 63;
  if (lane == 0) wc[wv] = (u32)__popcll(bal);
  __syncthreads();
  if (t == 0) { u32 a = 0; for (int i = 0; i < bx; ++i) a += cnts[i]; sbase = a; }
  __syncthreads();
  u32 base = sbase;
  for (int w = 0; w < wv; ++w) base += wc[w];
  u32 rank = (u32)__popcll(bal & ((1ull << lane) - 1ull));
  if (pred) {
    u32 pos = base + rank;
    if (pos < MAXC) cand[(size_t)b * MAXC + pos] = key;
  }
}

// ---------------- tile sort: 2048-element bitonic in LDS ----------------
#define SIDX(x) ((x) + ((x) >> 5))   // pad every 32 u64 to break bank aliasing
__global__ __launch_bounds__(1024) void k_sort_tile(u64* __restrict__ a)
{
  int b = blockIdx.y, base = blockIdx.x * 2048;
  u64* p = a + (size_t)b * MAXC + base;
  __shared__ u64 lds[2048 + 64];
  int t = threadIdx.x;
  lds[SIDX(t)] = p[t];
  lds[SIDX(t + 1024)] = p[t + 1024];
  __syncthreads();
  for (int k = 2; k <= 2048; k <<= 1) {
    for (int j = k >> 1; j > 0; j >>= 1) {
      int i = ((t & ~(j - 1)) << 1) | (t & (j - 1));
      int l = i | j;
      bool asc = ((i & k) == 0);
      u64 x = lds[SIDX(i)], y = lds[SIDX(l)];
      if ((x > y) == asc) { lds[SIDX(i)] = y; lds[SIDX(l)] = x; }
      __syncthreads();
    }
  }
  p[t] = lds[SIDX(t)];
  p[t + 1024] = lds[SIDX(t + 1024)];
}

// ---------------- merge-path ranking + fused gather ---------------------
__global__ __launch_bounds__(256) void k_merge_gather(
    const u64* __restrict__ cand, const float4* __restrict__ boxes,
    float4* __restrict__ gbox, u64* __restrict__ deadm)
{
  int b = blockIdx.y;
  int p = blockIdx.x * 256 + threadIdx.x;   // [0, MAXC)
  const u64* cb = cand + (size_t)b * MAXC;
  u64 key = cb[p];
  int r = p >> 11;
  int rank = p & 2047;
#pragma unroll
  for (int s = 0; s < NSEG; ++s) {
    if (s == r) continue;
    const u64* run = cb + (s << 11);
    int lo = 0;
#pragma unroll
    for (int step = 2048; step >= 1; step >>= 1) {
      int np = lo + step;
      if (np <= 2048 && run[np - 1] < key) lo = np;
    }
    rank += lo;
  }
  bool valid = ((u32)(key >> 32) < 0x80000000u) && (rank < N_PRE);
  float4 bx = make_float4(0.f, 0.f, 0.f, 0.f);
  if (valid) bx = boxes[(size_t)b * N_ANC + (u32)key];
  gbox[(size_t)b * MAXC + rank] = bx;
  if (!valid) atomicOr(&deadm[b * NDW + (rank >> 6)], 1ull << (rank & 63));
}

// ------ mask tile: reg row boxes + dead-row/dead-colword filtering ------
// Dead rows can never be kept, so their mask rows are don't-cares: write 0
// and skip the IoU. Monotone-safe vs concurrent cross/walk deadm updates.
template <int NWAVES>
__device__ __forceinline__ void segmask_tile_v3(
    int b, int sg, int tile, const float4* __restrict__ gbox,
    const u64* __restrict__ deadm,
    u64* __restrict__ smask, u64* __restrict__ smaskT, u64* diag)
{
  const int RPW = 64 / NWAVES;
  int r = tile, rg = 0;
  while (r >= 32 - rg) { r -= 32 - rg; ++rg; }
  int cw = rg + r;
  const float4* gb = gbox + (size_t)b * MAXC + sg * SEG;
  const u64* dmb = deadm + b * NDW + sg * NW;
  int t = threadIdx.x, wv = t >> 6, lane = t & 63;
  int rbase = rg * 64 + wv * RPW;
  bool isdiag = (cw == rg);
  u64 rowdead = dmb[rg];
  u64 coldead = dmb[cw];
  u64* srow = smask + (size_t)(b * NSEG + sg) * SEG * NW + (size_t)rg * 64 * NW;

  if (coldead == ~0ull) {             // whole column word dead: zero rows
    if (lane == 0) {
#pragma unroll
      for (int i = 0; i < RPW; ++i) {
        int rr = wv * RPW + i;
        srow[(size_t)rr * NW + cw] = 0;
        if (isdiag) diag[rr] = 0;
      }
    }
  } else {
    float4 rb[RPW];
#pragma unroll
    for (int i = 0; i < RPW; ++i) rb[i] = gb[rbase + i];
    float ra[RPW];
#pragma unroll
    for (int i = 0; i < RPW; ++i) ra[i] = area_of(rb[i]);
    float4 cb4 = gb[cw * 64 + lane];
    float ca = area_of(cb4);
#pragma unroll
    for (int i = 0; i < RPW; ++i) {
      int rr = wv * RPW + i;
      u64 m = 0;
      if (!((rowdead >> rr) & 1)) {   // wave-uniform row-dead skip
        bool p = iou_gt_a(rb[i], cb4, ra[i], ca);
        if (isdiag) p = p && (lane > rr);
        m = __ballot(p);
      }
      if (lane == 0) { srow[(size_t)rr * NW + cw] = m; if (isdiag) diag[rr] = m; }
    }
  }
  if (isdiag) {   // block-uniform condition
    __syncthreads();
    if (t < 64) {
      u64 s = 0;
      for (int q = 0; q < 64; ++q) s |= ((diag[q] >> t) & 1ull) << q;
      smaskT[(size_t)(b * NSEG + sg) * SEG + rg * 64 + t] = s;
    }
  }
}

// standalone mask build for segment 0 (256 threads, 4 waves/tile)
__global__ __launch_bounds__(256) void k_segmask(
    const float4* __restrict__ gbox, const u64* __restrict__ deadm,
    u64* __restrict__ smask, u64* __restrict__ smaskT, int sg)
{
  __shared__ u64 diag[64];
  segmask_tile_v3<4>(blockIdx.y, sg, blockIdx.x, gbox, deadm, smask, smaskT, diag);
}

// cross (sg candidates vs kept list)
__global__ __launch_bounds__(256) void k_cross(
    const float4* __restrict__ gbox, const float4* __restrict__ keptb,
    const int* __restrict__ meta, u64* __restrict__ deadm, int sg)
{
  int b = blockIdx.y;
  if (meta[b * 8 + 1]) return;
  __shared__ float4 kb[256]; __shared__ float ka[256];
  int kc = blockIdx.x >> 3, cbk = blockIdx.x & 7;
  int nkept = meta[b * 8 + 0];
  int kbase = kc * 256;
  if (kbase >= nkept) return;
  int kcnt = min(256, nkept - kbase);
  int t = threadIdx.x;
  if (t < kcnt) {
    float4 k4 = keptb[(size_t)b * SEG + kbase + t];
    kb[t] = k4; ka[t] = area_of(k4);
  }
  __syncthreads();
  int gi = sg * SEG + cbk * 256 + t;
  float4 my = gbox[(size_t)b * MAXC + gi];
  float ma = area_of(my);
  bool sup = false;
  for (int kk = 0; kk < kcnt; ++kk) {
    if (iou_gt_a(kb[kk], my, ka[kk], ma)) { sup = true; break; }
  }
  u64 bm = __ballot(sup);
  if ((t & 63) == 0 && bm) atomicOr(&deadm[b * NDW + (gi >> 6)], bm);
}

// ---------------- greedy walk body (R10 version: best measured) ---------
__device__ void walk_body(
    int b, int sg, const float4* __restrict__ gbox, const u64* smask,
    const u64* smaskT, const u64* __restrict__ deadm,
    int* __restrict__ meta, float4* __restrict__ keptb,
    float* __restrict__ out)
{
  int t = threadIdx.x, wv = t >> 6, lane = t & 63;

  __shared__ u64 rowbuf[2][2048];   // 32 KiB: 64 rows x 32 words, dbuf
  __shared__ u64 stbuf[2][64];
  __shared__ float4 bbox[2][64];
  __shared__ u64 sdead[2];
  __shared__ u32 remv[64];          // 2048 suppression bits (u32 halves)
  __shared__ u32 klist[64];
  __shared__ int s_stop, s_nkept, s_kcnt;

  const u64* smb = smask + (size_t)(b * NSEG + sg) * SEG * NW;
  const u64* stb = smaskT + (size_t)(b * NSEG + sg) * SEG;
  const u64* dmb = deadm + b * NDW + sg * NW;
  const float4* gb = gbox + (size_t)b * MAXC + sg * SEG;
  float4* kbuf = keptb + (size_t)b * SEG;
  float4* ob = (float4*)(out + (size_t)b * N_POST * 4);
  float* om = out + (size_t)B_SZ * N_POST * 4 + (size_t)b * N_POST;

  // prologue: stage group 0 directly (batched window)
  {
    u64 a = smb[t], c = smb[t + 1024];
    u64 st_ = 0; float4 bb_ = make_float4(0.f, 0.f, 0.f, 0.f);
    if (t < 64) { st_ = stb[t]; bb_ = gb[t]; }
    u64 sd_ = (t == 0) ? dmb[0] : 0;
    rowbuf[0][t] = a;
    rowbuf[0][t + 1024] = c;
    if (t < 64) { stbuf[0][t] = st_; bbox[0][t] = bb_; remv[t] = 0; }
    if (t == 0) { sdead[0] = sd_; s_stop = 0; s_nkept = meta[b * 8 + 0]; }
  }
  // issue group-1 loads into registers (staging waves), write next slot
  int p0 = t - 64, p1 = p0 + 960, p2 = p0 + 1920;
  u64 ra = 0, rc = 0, re = 0, rst = 0, rsd = 0;
  float4 rbb = make_float4(0.f, 0.f, 0.f, 0.f);
  if (wv > 0) {
    const u64* src = smb + 2048;
    ra = src[p0];
    rc = src[p1];
    if (p0 < 128) re = src[p2];
    if (p0 < 64) { rst = stb[64 + p0]; rbb = gb[64 + p0]; }
    if (t == 64) rsd = dmb[1];
  }
  __syncthreads();

  for (int g = 0; g < NW; ++g) {
    int cb = g & 1, nb = cb ^ 1;
    if (wv > 0) {
      if (g < NW - 1) {        // write group g+1 from regs (loads had 1 slot)
        rowbuf[nb][p0] = ra;
        rowbuf[nb][p1] = rc;
        if (p0 < 128) rowbuf[nb][p2] = re;
        if (p0 < 64) { stbuf[nb][p0] = rst; bbox[nb][p0] = rbb; }
        if (t == 64) sdead[nb] = rsd;
      }
      if (g < NW - 2) {        // issue group g+2 loads into regs
        const u64* src = smb + (size_t)(g + 2) * 2048;
        ra = src[p0];
        rc = src[p1];
        if (p0 < 128) re = src[p2];
        if (p0 < 64) { rst = stb[(g + 2) * 64 + p0]; rbb = gb[(g + 2) * 64 + p0]; }
        if (t == 64) rsd = dmb[g + 2];
      }
    } else {                   // wave 0: resolve group g
      int l = lane;
      u64 S = stbuf[cb][l];
      u64 remg = ((u64)remv[2 * g + 1] << 32) | remv[2 * g];
      u64 avail = ~(remg | sdead[cb]);
      u64 km = 0;
      while (avail) {
        bool al = (avail >> l) & 1;
        u64 newk = __ballot(al && (S & avail) == 0ull);
        u64 nd   = __ballot(al && (S & newk) != 0ull);
        km |= newk;
        avail &= ~(newk | nd);
      }
      int nk0 = s_nkept;
      int rem = N_POST - nk0;
      int kc = __popcll(km);
      bool stop = (kc >= rem);
      int rank = __popcll(km & ((1ull << l) - 1ull));
      if (((km >> l) & 1) && rank < rem) {
        float4 bx = bbox[cb][l];
        kbuf[nk0 + rank] = bx;
        ob[nk0 + rank] = bx;            // write output directly
        om[nk0 + rank] = 1.0f;
        klist[rank] = (u32)l;
      }
      if (l == 0) {
        int eff = stop ? rem : kc;
        s_kcnt = eff;
        s_nkept = nk0 + eff;
        if (stop) s_stop = 1;
      }
    }
    __syncthreads();
    if (s_stop) break;
    if (g < NW - 1) {
      // stage C: all 1024 threads OR kept rows' future words into remv
      int kcnt = s_kcnt;
      if (kcnt) {
        u32* rb32 = (u32*)rowbuf[cb];
        for (int i = t; i < kcnt * 64; i += 1024) {
          int kk = i >> 6, w = i & 63;
          if ((w >> 1) > g) {
            u32 v = rb32[klist[kk] * 64 + w];
            if (v) atomicOr(&remv[w], v);
          }
        }
      }
    }
    __syncthreads();
  }
  int nk = s_nkept;
  bool fin = s_stop || (sg == NSEG - 1);
  if (t == 0) { meta[b * 8 + 0] = nk; if (fin) meta[b * 8 + 1] = 1; }
  if (fin) {  // zero-pad tail of outputs
    float4 zero = make_float4(0.f, 0.f, 0.f, 0.f);
    for (int i = nk + t; i < N_POST; i += 1024) { ob[i] = zero; om[i] = 0.0f; }
  }
}

// ---- fused: walk(sg) [block 0] || lean v3 mask(msg) [blocks 1..528] ----
__global__ __launch_bounds__(1024) void k_walkmask(
    const float4* __restrict__ gbox, u64* smask, u64* smaskT,
    const u64* __restrict__ deadm, int* __restrict__ meta,
    float4* __restrict__ keptb, float* __restrict__ out, int sg, int msg)
{
  __shared__ u64 diag[64];
  int b = blockIdx.y;
  if (meta[b * 8 + 1]) return;   // done (uniform per batch)
  if (blockIdx.x == 0) {
    walk_body(b, sg, gbox, smask, smaskT, deadm, meta, keptb, out);
  } else {
    if (msg < 0 || msg >= NSEG) return;
    segmask_tile_v3<16>(b, msg, blockIdx.x - 1, gbox, deadm, smask, smaskT, diag);
  }
}

extern "C" void kernel_launch(void* const* d_in, const int* in_sizes, int n_in,
                              void* d_out, int out_size, void* d_ws, size_t ws_size,
                              hipStream_t stream)
{
  const int*   imh     = (const int*)d_in[0];
  const int*   imw     = (const int*)d_in[1];
  const float* anchors = (const float*)d_in[2];
  const float* loc     = (const float*)d_in[3];
  const float* obj     = (const float*)d_in[4];
  float* out = (float*)d_out;

  char* ws = (char*)d_ws;
  size_t off = 0;
  float4* boxes = (float4*)(ws + off); off += (size_t)B_SZ * N_ANC * 16;
  u64*    keys  = (u64*)   (ws + off); off += (size_t)B_SZ * N_ANC * 8;
  u64*    cand  = (u64*)   (ws + off); off += (size_t)B_SZ * MAXC * 8;
  float4* gbox  = (float4*)(ws + off); off += (size_t)B_SZ * MAXC * 16;
  float4* keptb = (float4*)(ws + off); off += (size_t)B_SZ * SEG * 16;
  off = (off + 255) & ~(size_t)255;
  char*   zr    = ws + off;  // zeroed region
  u32*    hist1 = (u32*)(zr);
  u32*    hist2 = (u32*)(zr + 65536);
  u32*    T1    = (u32*)(zr + 131072);
  u32*    Base1 = (u32*)(zr + 131072 + 32);
  u32*    T2    = (u32*)(zr + 131072 + 64);
  u32*    need2 = (u32*)(zr + 131072 + 96);
  int*    meta  = (int*)(zr + 131072 + 128);                 // 8*8 ints
  u64*    deadm = (u64*)(zr + 131072 + 128 + 256);           // 12 KiB
  u32*    bcnt  = (u32*)(zr + 131072 + 128 + 256 + (size_t)B_SZ * NDW * 8);
  size_t  zr_sz = 131072 + 128 + 256 + (size_t)B_SZ * NDW * 8
                + (size_t)B_SZ * NBLK * 4;
  off += (zr_sz + 255) & ~(size_t)255;
  u64*    smask  = (u64*)(ws + off); off += (size_t)B_SZ * NSEG * SEG * NW * 8;
  u64*    smaskT = (u64*)(ws + off); off += (size_t)B_SZ * NSEG * SEG * 8;

  hipMemsetAsync(zr, 0, zr_sz, stream);
  hipMemsetAsync(cand, 0xFF, (size_t)B_SZ * MAXC * 8, stream);

  k_decode<<<dim3(NBLK, B_SZ), 256, 0, stream>>>(imh, imw, anchors, loc, obj,
                                                 boxes, keys, hist1);
  k_pick1<<<B_SZ, 256, 0, stream>>>(hist1, T1, Base1, T2, need2);
  k_hist2<<<dim3(36, B_SZ), 256, 0, stream>>>(keys, T1, need2, hist2);
  k_pick2<<<B_SZ, 256, 0, stream>>>(hist2, T1, Base1, need2, T2);

  k_count<<<dim3(NBLK, B_SZ), 256, 0, stream>>>(keys, T2, bcnt);
  k_scatter<<<dim3(NBLK, B_SZ), 256, 0, stream>>>(keys, T2, bcnt, cand);

  k_sort_tile<<<dim3(NSEG, B_SZ), 1024, 0, stream>>>(cand);
  k_merge_gather<<<dim3(MAXC / 256, B_SZ), 256, 0, stream>>>(cand, boxes, gbox, deadm);

  // mask seg0 standalone, then walk(sg) || mask(sg+1) fused, cross between
  k_segmask<<<dim3(528, B_SZ), 256, 0, stream>>>(gbox, deadm, smask, smaskT, 0);

  k_walkmask<<<dim3(529, B_SZ), 1024, 0, stream>>>(gbox, smask, smaskT, deadm,
                                                   meta, keptb, out, 0, 1);
  for (int sg = 1; sg < NSEG; ++sg) {
    k_cross<<<dim3(64, B_SZ), 256, 0, stream>>>(gbox, keptb, meta, deadm, sg);
    int msg = (sg + 1 < NSEG) ? sg + 1 : -1;
    int gx = (msg >= 0) ? 529 : 1;
    k_walkmask<<<dim3(gx, B_SZ), 1024, 0, stream>>>(gbox, smask, smaskT, deadm,
                                                    meta, keptb, out, sg, msg);
  }
}

// Round 17
// 216.788 us; speedup vs baseline: 1.1720x; 1.1720x over previous
//
#include <hip/hip_runtime.h>

typedef unsigned long long u64;
typedef unsigned int u32;

#define B_SZ   8
#define N_ANC  36864
#define N_PRE  12000
#define N_POST 2000
#define SEG    2048
#define NSEG   6
#define MAXC   (SEG * NSEG)   // 12288
#define NW     (SEG / 64)     // 32 u64 words per mask row
#define NDW    (MAXC / 64)    // 192 dead-mask words per batch
#define NBLK   144            // decode/scatter blocks per batch

__device__ __forceinline__ float area_of(float4 p) {
  return __fmul_rn(__fsub_rn(p.z, p.x), __fsub_rn(p.w, p.y));
}

// bit-exact replication: a0 = area(first reference arg), a1 = area(second)
__device__ __forceinline__ bool iou_gt_a(float4 p, float4 q, float a0, float a1) {
  float ix1 = fmaxf(p.x, q.x), iy1 = fmaxf(p.y, q.y);
  float ix2 = fminf(p.z, q.z), iy2 = fminf(p.w, q.w);
  float iw = fmaxf(__fsub_rn(ix2, ix1), 0.0f);
  float ih = fmaxf(__fsub_rn(iy2, iy1), 0.0f);
  float inter = __fmul_rn(iw, ih);
  float den = fmaxf(__fsub_rn(__fadd_rn(a0, a1), inter), 1e-9f);
  return (inter / den) > 0.7f;
}

// ---------------- decode + score + keys + fused level-1 histogram -------
__global__ __launch_bounds__(256) void k_decode(
    const int* __restrict__ imh_p, const int* __restrict__ imw_p,
    const float* __restrict__ anchors, const float* __restrict__ loc,
    const float* __restrict__ obj, float4* __restrict__ boxes,
    u64* __restrict__ keys, u32* __restrict__ hist)
{
  __shared__ u32 lh[2048];
  int t = threadIdx.x;
#pragma unroll
  for (int i = 0; i < 8; ++i) lh[t + i * 256] = 0;
  __syncthreads();

  int n = blockIdx.x * 256 + t;
  int b = blockIdx.y;
  float a0 = anchors[n * 4 + 0], a1 = anchors[n * 4 + 1];
  float a2 = anchors[n * 4 + 2], a3 = anchors[n * 4 + 3];
  size_t off = (size_t)b * N_ANC + n;
  float l0 = loc[off * 4 + 0], l1 = loc[off * 4 + 1];
  float l2 = loc[off * 4 + 2], l3 = loc[off * 4 + 3];

  float w  = __fsub_rn(a2, a0);
  float h  = __fsub_rn(a3, a1);
  float cx = __fadd_rn(a0, __fmul_rn(0.5f, w));
  float cy = __fadd_rn(a1, __fmul_rn(0.5f, h));
  float pcx = __fadd_rn(__fmul_rn(l0, w), cx);
  float pcy = __fadd_rn(__fmul_rn(l1, h), cy);
  float pw  = __fmul_rn(expf(l2), w);
  float ph  = __fmul_rn(expf(l3), h);
  float imw = (float)imw_p[0], imh = (float)imh_p[0];
  float hx = __fmul_rn(0.5f, pw), hy = __fmul_rn(0.5f, ph);
  float x1 = fminf(fmaxf(__fsub_rn(pcx, hx), 0.0f), imw);
  float y1 = fminf(fmaxf(__fsub_rn(pcy, hy), 0.0f), imh);
  float x2 = fminf(fmaxf(__fadd_rn(pcx, hx), 0.0f), imw);
  float y2 = fminf(fmaxf(__fadd_rn(pcy, hy), 0.0f), imh);
  boxes[off] = make_float4(x1, y1, x2, y2);

  bool valid = (__fsub_rn(x2, x1) >= 16.0f) && (__fsub_rn(y2, y1) >= 16.0f);

  float o0 = obj[off * 2 + 0], o1 = obj[off * 2 + 1];
  float m  = fmaxf(o0, o1);
  float e0 = expf(__fsub_rn(o0, m));
  float e1 = expf(__fsub_rn(o1, m));
  float s  = e1 / __fadd_rn(e0, e1);
  float sc = valid ? s : -1e9f;

  u32 u  = __float_as_uint(sc);
  u32 fk = (u & 0x80000000u) ? ~u : (u | 0x80000000u);
  u32 sk = ~fk;  // ascending u64 == descending score, stable by index
  u64 key = ((u64)sk << 32) | (u32)n;
  keys[off] = key;
  atomicAdd(&lh[(u32)(key >> 53)], 1u);
  __syncthreads();
#pragma unroll
  for (int i = 0; i < 8; ++i) {
    u32 v = lh[t + i * 256];
    if (v) atomicAdd(&hist[b * 2048 + t + i * 256], v);
  }
}

// ---------------- level-1 pick ------------------------------------------
__global__ __launch_bounds__(256) void k_pick1(
    const u32* __restrict__ hist, u32* __restrict__ T1, u32* __restrict__ Base1)
{
  int b = blockIdx.x, t = threadIdx.x;
  const u32* h = hist + b * 2048;
  __shared__ u32 part[256], pre[256];
  u32 loc[8], s = 0;
#pragma unroll
  for (int i = 0; i < 8; ++i) { loc[i] = h[t * 8 + i]; s += loc[i]; }
  part[t] = s;
  __syncthreads();
  if (t == 0) { u32 acc = 0; for (int i = 0; i < 256; ++i) { pre[i] = acc; acc += part[i]; } }
  __syncthreads();
  u32 acc = pre[t];
#pragma unroll
  for (int i = 0; i < 8; ++i) {
    u32 na = acc + loc[i];
    if (acc < N_PRE && na >= N_PRE) { T1[b] = (u32)(t * 8 + i); Base1[b] = acc; }
    acc = na;
  }
}

// ---------------- level-2 histogram (always on) -------------------------
__global__ __launch_bounds__(256) void k_hist2(
    const u64* __restrict__ keys, const u32* __restrict__ T1,
    u32* __restrict__ hist)
{
  int b = blockIdx.y;
  u32 t1 = T1[b];
  __shared__ u32 lh[2048];
  int t = threadIdx.x;
#pragma unroll
  for (int i = 0; i < 8; ++i) lh[t + i * 256] = 0;
  __syncthreads();
#pragma unroll
  for (int k = 0; k < 4; ++k) {
    int i = blockIdx.x * 1024 + k * 256 + t;
    u64 key = keys[(size_t)b * N_ANC + i];
    if ((u32)(key >> 53) == t1) atomicAdd(&lh[(u32)(key >> 42) & 0x7FFu], 1u);
  }
  __syncthreads();
#pragma unroll
  for (int i = 0; i < 8; ++i) {
    u32 v = lh[t + i * 256];
    if (v) atomicAdd(&hist[b * 2048 + t + i * 256], v);
  }
}

__global__ __launch_bounds__(256) void k_pick2(
    const u32* __restrict__ hist, const u32* __restrict__ T1,
    const u32* __restrict__ Base1, u32* __restrict__ T2)
{
  int b = blockIdx.x, t = threadIdx.x;
  const u32* h = hist + b * 2048;
  __shared__ u32 part[256], pre[256];
  u32 loc[8], s = 0;
#pragma unroll
  for (int i = 0; i < 8; ++i) { loc[i] = h[t * 8 + i]; s += loc[i]; }
  part[t] = s;
  __syncthreads();
  if (t == 0) { u32 acc = Base1[b]; for (int i = 0; i < 256; ++i) { pre[i] = acc; acc += part[i]; } }
  __syncthreads();
  u32 acc = pre[t];
#pragma unroll
  for (int i = 0; i < 8; ++i) {
    u32 na = acc + loc[i];
    if (acc < N_PRE && na >= N_PRE) T2[b] = (T1[b] << 11) | (u32)(t * 8 + i);
    acc = na;
  }
}

// ---------------- compact: count -> scatter (scatter self-scans) --------
__global__ __launch_bounds__(256) void k_count(
    const u64* __restrict__ keys, const u32* __restrict__ T2,
    u32* __restrict__ bcnt)
{
  int b = blockIdx.y;
  int i = blockIdx.x * 256 + threadIdx.x;
  u64 key = keys[(size_t)b * N_ANC + i];
  bool pred = (u32)(key >> 42) <= T2[b];
  u64 bal = __ballot(pred);
  __shared__ u32 wc[4];
  int wv = threadIdx.x >> 6, lane = threadIdx.x & 63;
  if (lane == 0) wc[wv] = (u32)__popcll(bal);
  __syncthreads();
  if (threadIdx.x == 0)
    bcnt[b * NBLK + blockIdx.x] = wc[0] + wc[1] + wc[2] + wc[3];
}

__global__ __launch_bounds__(256) void k_scatter(
    const u64* __restrict__ keys, const u32* __restrict__ T2,
    const u32* __restrict__ bcnt, u64* __restrict__ cand)
{
  int b = blockIdx.y, bx = blockIdx.x;
  int t = threadIdx.x;
  __shared__ u32 cnts[NBLK];
  __shared__ u32 wc[4];
  __shared__ u32 sbase;
  if (t < NBLK) cnts[t] = bcnt[b * NBLK + t];
  u64 key = keys[(size_t)b * N_ANC + bx * 256 + t];
  bool pred = (u32)(key >> 42) <= T2[b];
  u64 bal = __ballot(pred);
  int wv = t >> 6, lane = t & 63;
  if (lane == 0) wc[wv] = (u32)__popcll(bal);
  __syncthreads();
  if (t == 0) { u32 a = 0; for (int i = 0; i < bx; ++i) a += cnts[i]; sbase = a; }
  __syncthreads();
  u32 base = sbase;
  for (int w = 0; w < wv; ++w) base += wc[w];
  u32 rank = (u32)__popcll(bal & ((1ull << lane) - 1ull));
  if (pred) {
    u32 pos = base + rank;
    if (pos < MAXC) cand[(size_t)b * MAXC + pos] = key;
  }
}

// ---------------- tile sort: 2048-element bitonic in LDS ----------------
#define SIDX(x) ((x) + ((x) >> 5))   // pad every 32 u64 to break bank aliasing
__global__ __launch_bounds__(1024) void k_sort_tile(u64* __restrict__ a)
{
  int b = blockIdx.y, base = blockIdx.x * 2048;
  u64* p = a + (size_t)b * MAXC + base;
  __shared__ u64 lds[2048 + 64];
  int t = threadIdx.x;
  lds[SIDX(t)] = p[t];
  lds[SIDX(t + 1024)] = p[t + 1024];
  __syncthreads();
  for (int k = 2; k <= 2048; k <<= 1) {
    for (int j = k >> 1; j > 0; j >>= 1) {
      int i = ((t & ~(j - 1)) << 1) | (t & (j - 1));
      int l = i | j;
      bool asc = ((i & k) == 0);
      u64 x = lds[SIDX(i)], y = lds[SIDX(l)];
      if ((x > y) == asc) { lds[SIDX(i)] = y; lds[SIDX(l)] = x; }
      __syncthreads();
    }
  }
  p[t] = lds[SIDX(t)];
  p[t + 1024] = lds[SIDX(t + 1024)];
}

// ---------------- merge-path ranking + fused gather ---------------------
__global__ __launch_bounds__(256) void k_merge_gather(
    const u64* __restrict__ cand, const float4* __restrict__ boxes,
    float4* __restrict__ gbox, u64* __restrict__ deadm)
{
  int b = blockIdx.y;
  int p = blockIdx.x * 256 + threadIdx.x;   // [0, MAXC)
  const u64* cb = cand + (size_t)b * MAXC;
  u64 key = cb[p];
  int r = p >> 11;
  int rank = p & 2047;
#pragma unroll
  for (int s = 0; s < NSEG; ++s) {
    if (s == r) continue;
    const u64* run = cb + (s << 11);
    int lo = 0;
#pragma unroll
    for (int step = 2048; step >= 1; step >>= 1) {
      int np = lo + step;
      if (np <= 2048 && run[np - 1] < key) lo = np;
    }
    rank += lo;
  }
  bool valid = ((u32)(key >> 32) < 0x80000000u) && (rank < N_PRE);
  float4 bx = make_float4(0.f, 0.f, 0.f, 0.f);
  if (valid) bx = boxes[(size_t)b * N_ANC + (u32)key];
  gbox[(size_t)b * MAXC + rank] = bx;
  if (!valid) atomicOr(&deadm[b * NDW + (rank >> 6)], 1ull << (rank & 63));
}

// ---------------- balanced 64x64 mask tile ------------------------------
__device__ __forceinline__ void segmask_tile(
    int b, int sg, int tile, const float4* __restrict__ gbox,
    u64* __restrict__ smask, u64* __restrict__ smaskT,
    float4* rbox, float* rarea, u64* diag)
{
  int r = tile, rg = 0;
  while (r >= 32 - rg) { r -= 32 - rg; ++rg; }
  int cw = rg + r;
  const float4* gb = gbox + (size_t)b * MAXC + sg * SEG;
  int t = threadIdx.x;
  if (t < 64) { float4 bx = gb[rg * 64 + t]; rbox[t] = bx; rarea[t] = area_of(bx); }
  __syncthreads();
  int wv = t >> 6, lane = t & 63;
  u64* srow = smask + (size_t)(b * NSEG + sg) * SEG * NW + (size_t)rg * 64 * NW;
  float4 cb4 = gb[cw * 64 + lane];
  float ca = area_of(cb4);
  bool isdiag = (cw == rg);
  for (int rr = wv * 16; rr < wv * 16 + 16; ++rr) {
    bool p = iou_gt_a(rbox[rr], cb4, rarea[rr], ca);
    if (isdiag) p = p && (lane > rr);
    u64 m = __ballot(p);
    if (lane == 0) { srow[(size_t)rr * NW + cw] = m; if (isdiag) diag[rr] = m; }
  }
  if (isdiag) {
    __syncthreads();
    if (t < 64) {
      u64 s = 0;
      for (int q = 0; q < 64; ++q) s |= ((diag[q] >> t) & 1ull) << q;
      smaskT[(size_t)(b * NSEG + sg) * SEG + rg * 64 + t] = s;
    }
  }
}

__global__ __launch_bounds__(256) void k_segmask01(
    const float4* __restrict__ gbox, u64* __restrict__ smask,
    u64* __restrict__ smaskT)
{
  __shared__ float4 rbox[64]; __shared__ float rarea[64]; __shared__ u64 diag[64];
  int b = blockIdx.y;
  int sg = blockIdx.x / 528, tile = blockIdx.x % 528;
  segmask_tile(b, sg, tile, gbox, smask, smaskT, rbox, rarea, diag);
}

// cross (sg candidates vs kept list)
__device__ __forceinline__ void cross_work(
    int b, int sg, int bx, const float4* __restrict__ gbox,
    const float4* __restrict__ keptb, const int* __restrict__ meta,
    u64* __restrict__ deadm, float4* kb, float* ka)
{
  int kc = bx >> 3, cbk = bx & 7;
  int nkept = meta[b * 8 + 0];
  int kbase = kc * 256;
  if (kbase >= nkept) return;
  int kcnt = min(256, nkept - kbase);
  int t = threadIdx.x;
  if (t < kcnt) {
    float4 k4 = keptb[(size_t)b * SEG + kbase + t];
    kb[t] = k4; ka[t] = area_of(k4);
  }
  __syncthreads();
  int gi = sg * SEG + cbk * 256 + t;
  float4 my = gbox[(size_t)b * MAXC + gi];
  float ma = area_of(my);
  bool sup = false;
  for (int kk = 0; kk < kcnt; ++kk) {
    if (iou_gt_a(kb[kk], my, ka[kk], ma)) { sup = true; break; }
  }
  u64 bm = __ballot(sup);
  if ((t & 63) == 0 && bm) atomicOr(&deadm[b * NDW + (gi >> 6)], bm);
}

__global__ __launch_bounds__(256) void k_cross(
    const float4* __restrict__ gbox, const float4* __restrict__ keptb,
    const int* __restrict__ meta, u64* __restrict__ deadm, int sg)
{
  int b = blockIdx.y;
  if (meta[b * 8 + 1]) return;
  __shared__ float4 kb[256]; __shared__ float ka[256];
  cross_work(b, sg, blockIdx.x, gbox, keptb, meta, deadm, kb, ka);
}

// fused cross + gated segmask for sg>=2
__global__ __launch_bounds__(256) void k_crossmask(
    const float4* __restrict__ gbox, const float4* __restrict__ keptb,
    const int* __restrict__ meta, u64* __restrict__ deadm,
    u64* __restrict__ smask, u64* __restrict__ smaskT, int sg)
{
  int b = blockIdx.y;
  if (meta[b * 8 + 1]) return;
  __shared__ float4 kb[256]; __shared__ float ka[256]; __shared__ u64 diag[64];
  if (blockIdx.x < 64) {
    cross_work(b, sg, blockIdx.x, gbox, keptb, meta, deadm, kb, ka);
  } else {
    segmask_tile(b, sg, blockIdx.x - 64, gbox, smask, smaskT,
                 kb, ka, diag);
  }
}

// ---------------- greedy walk: ballot fixpoint + T14 pipelined staging --
__global__ __launch_bounds__(1024) void k_walk(
    const float4* __restrict__ gbox, const u64* __restrict__ smask,
    const u64* __restrict__ smaskT, const u64* __restrict__ deadm,
    int* __restrict__ meta, float4* __restrict__ keptb,
    float* __restrict__ out, int sg)
{
  int b = blockIdx.x;
  if (meta[b * 8 + 1]) return;
  int t = threadIdx.x, wv = t >> 6, lane = t & 63;

  __shared__ u64 rowbuf[2][2048];   // 32 KiB: 64 rows x 32 words, dbuf
  __shared__ u64 stbuf[2][64];
  __shared__ float4 bbox[2][64];
  __shared__ u64 sdead[2];
  __shared__ u32 remv[64];          // 2048 suppression bits (u32 halves)
  __shared__ u32 klist[64];
  __shared__ int s_stop, s_nkept, s_kcnt;

  const u64* smb = smask + (size_t)(b * NSEG + sg) * SEG * NW;
  const u64* stb = smaskT + (size_t)(b * NSEG + sg) * SEG;
  const u64* dmb = deadm + b * NDW + sg * NW;
  const float4* gb = gbox + (size_t)b * MAXC + sg * SEG;
  float4* kbuf = keptb + (size_t)b * SEG;
  float4* ob = (float4*)(out + (size_t)b * N_POST * 4);
  float* om = out + (size_t)B_SZ * N_POST * 4 + (size_t)b * N_POST;

  // prologue: stage group 0 directly (batched window)
  {
    u64 a = smb[t], c = smb[t + 1024];
    u64 st_ = 0; float4 bb_ = make_float4(0.f, 0.f, 0.f, 0.f);
    if (t < 64) { st_ = stb[t]; bb_ = gb[t]; }
    u64 sd_ = (t == 0) ? dmb[0] : 0;
    rowbuf[0][t] = a;
    rowbuf[0][t + 1024] = c;
    if (t < 64) { stbuf[0][t] = st_; bbox[0][t] = bb_; remv[t] = 0; }
    if (t == 0) { sdead[0] = sd_; s_stop = 0; s_nkept = meta[b * 8 + 0]; }
  }
  // issue group-1 loads into registers (staging waves), write next slot
  int p0 = t - 64, p1 = p0 + 960, p2 = p0 + 1920;  // staging indices (wv>0)
  u64 ra = 0, rc = 0, re = 0, rst = 0, rsd = 0;
  float4 rbb = make_float4(0.f, 0.f, 0.f, 0.f);
  if (wv > 0) {
    const u64* src = smb + 2048;
    ra = src[p0];
    rc = src[p1];
    if (p0 < 128) re = src[p2];
    if (p0 < 64) { rst = stb[64 + p0]; rbb = gb[64 + p0]; }
    if (t == 64) rsd = dmb[1];
  }
  __syncthreads();

  for (int g = 0; g < NW; ++g) {
    int cb = g & 1, nb = cb ^ 1;
    if (wv > 0) {
      if (g < NW - 1) {        // write group g+1 from regs (loads had 1 slot)
        rowbuf[nb][p0] = ra;
        rowbuf[nb][p1] = rc;
        if (p0 < 128) rowbuf[nb][p2] = re;
        if (p0 < 64) { stbuf[nb][p0] = rst; bbox[nb][p0] = rbb; }
        if (t == 64) sdead[nb] = rsd;
      }
      if (g < NW - 2) {        // issue group g+2 loads into regs
        const u64* src = smb + (size_t)(g + 2) * 2048;
        ra = src[p0];
        rc = src[p1];
        if (p0 < 128) re = src[p2];
        if (p0 < 64) { rst = stb[(g + 2) * 64 + p0]; rbb = gb[(g + 2) * 64 + p0]; }
        if (t == 64) rsd = dmb[g + 2];
      }
    } else {                   // wave 0: resolve group g
      int l = lane;
      u64 S = stbuf[cb][l];
      u64 remg = ((u64)remv[2 * g + 1] << 32) | remv[2 * g];
      u64 avail = ~(remg | sdead[cb]);
      u64 km = 0;
      while (avail) {
        bool al = (avail >> l) & 1;
        u64 newk = __ballot(al && (S & avail) == 0ull);
        u64 nd   = __ballot(al && (S & newk) != 0ull);
        km |= newk;
        avail &= ~(newk | nd);
      }
      int nk0 = s_nkept;
      int rem = N_POST - nk0;
      int kc = __popcll(km);
      bool stop = (kc >= rem);
      int rank = __popcll(km & ((1ull << l) - 1ull));
      if (((km >> l) & 1) && rank < rem) {
        float4 bx = bbox[cb][l];
        kbuf[nk0 + rank] = bx;
        ob[nk0 + rank] = bx;            // write output directly
        om[nk0 + rank] = 1.0f;
        klist[rank] = (u32)l;
      }
      if (l == 0) {
        int eff = stop ? rem : kc;
        s_kcnt = eff;
        s_nkept = nk0 + eff;
        if (stop) s_stop = 1;
      }
    }
    __syncthreads();
    if (s_stop) break;
    if (g < NW - 1) {
      // stage C: all 1024 threads OR kept rows' future words into remv
      int kcnt = s_kcnt;
      if (kcnt) {
        u32* rb32 = (u32*)rowbuf[cb];
        for (int i = t; i < kcnt * 64; i += 1024) {
          int kk = i >> 6, w = i & 63;
          if ((w >> 1) > g) {
            u32 v = rb32[klist[kk] * 64 + w];
            if (v) atomicOr(&remv[w], v);
          }
        }
      }
    }
    __syncthreads();
  }
  int nk = s_nkept;
  bool fin = s_stop || (sg == NSEG - 1);
  if (t == 0) { meta[b * 8 + 0] = nk; if (fin) meta[b * 8 + 1] = 1; }
  if (fin) {  // zero-pad tail of outputs
    float4 zero = make_float4(0.f, 0.f, 0.f, 0.f);
    for (int i = nk + t; i < N_POST; i += 1024) { ob[i] = zero; om[i] = 0.0f; }
  }
}

extern "C" void kernel_launch(void* const* d_in, const int* in_sizes, int n_in,
                              void* d_out, int out_size, void* d_ws, size_t ws_size,
                              hipStream_t stream)
{
  const int*   imh     = (const int*)d_in[0];
  const int*   imw     = (const int*)d_in[1];
  const float* anchors = (const float*)d_in[2];
  const float* loc     = (const float*)d_in[3];
  const float* obj     = (const float*)d_in[4];
  float* out = (float*)d_out;

  char* ws = (char*)d_ws;
  size_t off = 0;
  float4* boxes = (float4*)(ws + off); off += (size_t)B_SZ * N_ANC * 16;
  u64*    keys  = (u64*)   (ws + off); off += (size_t)B_SZ * N_ANC * 8;
  u64*    cand  = (u64*)   (ws + off); off += (size_t)B_SZ * MAXC * 8;
  float4* gbox  = (float4*)(ws + off); off += (size_t)B_SZ * MAXC * 16;
  float4* keptb = (float4*)(ws + off); off += (size_t)B_SZ * SEG * 16;
  off = (off + 255) & ~(size_t)255;
  char*   zr    = ws + off;  // zeroed region
  u32*    hist1 = (u32*)(zr);
  u32*    hist2 = (u32*)(zr + 65536);
  u32*    T1    = (u32*)(zr + 131072);
  u32*    Base1 = (u32*)(zr + 131072 + 32);
  u32*    T2    = (u32*)(zr + 131072 + 64);
  int*    meta  = (int*)(zr + 131072 + 128);                 // 8*8 ints
  u64*    deadm = (u64*)(zr + 131072 + 128 + 256);           // 12 KiB
  u32*    bcnt  = (u32*)(zr + 131072 + 128 + 256 + (size_t)B_SZ * NDW * 8);
  size_t  zr_sz = 131072 + 128 + 256 + (size_t)B_SZ * NDW * 8
                + (size_t)B_SZ * NBLK * 4;
  off += (zr_sz + 255) & ~(size_t)255;
  u64*    smask  = (u64*)(ws + off); off += (size_t)B_SZ * NSEG * SEG * NW * 8;
  u64*    smaskT = (u64*)(ws + off); off += (size_t)B_SZ * NSEG * SEG * 8;

  hipMemsetAsync(zr, 0, zr_sz, stream);
  hipMemsetAsync(cand, 0xFF, (size_t)B_SZ * MAXC * 8, stream);

  k_decode<<<dim3(NBLK, B_SZ), 256, 0, stream>>>(imh, imw, anchors, loc, obj,
                                                 boxes, keys, hist1);
  k_pick1<<<B_SZ, 256, 0, stream>>>(hist1, T1, Base1);
  k_hist2<<<dim3(36, B_SZ), 256, 0, stream>>>(keys, T1, hist2);
  k_pick2<<<B_SZ, 256, 0, stream>>>(hist2, T1, Base1, T2);

  k_count<<<dim3(NBLK, B_SZ), 256, 0, stream>>>(keys, T2, bcnt);
  k_scatter<<<dim3(NBLK, B_SZ), 256, 0, stream>>>(keys, T2, bcnt, cand);

  k_sort_tile<<<dim3(NSEG, B_SZ), 1024, 0, stream>>>(cand);
  k_merge_gather<<<dim3(MAXC / 256, B_SZ), 256, 0, stream>>>(cand, boxes, gbox, deadm);

  k_segmask01<<<dim3(1056, B_SZ), 256, 0, stream>>>(gbox, smask, smaskT);

  k_walk<<<B_SZ, 1024, 0, stream>>>(gbox, smask, smaskT, deadm, meta, keptb, out, 0);
  k_cross<<<dim3(64, B_SZ), 256, 0, stream>>>(gbox, keptb, meta, deadm, 1);
  k_walk<<<B_SZ, 1024, 0, stream>>>(gbox, smask, smaskT, deadm, meta, keptb, out, 1);
  for (int sg = 2; sg < NSEG; ++sg) {
    k_crossmask<<<dim3(592, B_SZ), 256, 0, stream>>>(gbox, keptb, meta, deadm,
                                                     smask, smaskT, sg);
    k_walk<<<B_SZ, 1024, 0, stream>>>(gbox, smask, smaskT, deadm, meta, keptb, out, sg);
  }
}